// Round 1
// baseline (610.844 us; speedup 1.0000x reference)
//
#include <hip/hip_runtime.h>

// LoraLinear NF4: out = x @ W_eff^T, W_eff = NF4[codes]*absmax + 2*(lora_B @ lora_A)
// M=8192 (4*2048), N=4096, K=4096. f16 MFMA GEMM (m97 structure: 128x128 tile,
// BK=32, 4 waves, 4x4 acc/wave, global_load_lds width=16).

typedef _Float16 half8 __attribute__((ext_vector_type(8)));
typedef float f32x4 __attribute__((ext_vector_type(4)));

#define M_DIM 8192
#define N_DIM 4096
#define K_DIM 4096

__constant__ float NF4C[16] = {
    -1.0f, -0.6961928009986877f, -0.5250730514526367f, -0.39491748809814453f,
    -0.28444138169288635f, -0.18477343022823334f, -0.09105003625154495f, 0.0f,
    0.07958029955625534f, 0.16093020141124725f, 0.24611230194568634f, 0.33791524171829224f,
    0.44070982933044434f, 0.5626170039176941f, 0.7229568362236023f, 1.0f};

__device__ __forceinline__ void gl16(void* lds, const void* g) {
  // async global->LDS, 16B/lane; LDS dest = wave-uniform base + lane*16
  __builtin_amdgcn_global_load_lds(
      (const __attribute__((address_space(1))) void*)g,
      (__attribute__((address_space(3))) void*)lds, 16, 0, 0);
}

// ---------------- prep_x: fp32 -> f16 cast of x ----------------
__global__ __launch_bounds__(256) void prep_x(const float4* __restrict__ x,
                                              half8* __restrict__ xh) {
  size_t i = (size_t)blockIdx.x * 256 + threadIdx.x;  // one half8 (8 elems) per thread
  float4 a = x[2 * i];
  float4 b = x[2 * i + 1];
  half8 h;
  h[0] = (_Float16)a.x; h[1] = (_Float16)a.y; h[2] = (_Float16)a.z; h[3] = (_Float16)a.w;
  h[4] = (_Float16)b.x; h[5] = (_Float16)b.y; h[6] = (_Float16)b.z; h[7] = (_Float16)b.w;
  xh[i] = h;
}

// ---------------- prep_w: dequant NF4 + fold 2*B@A, write f16 ----------------
// One block per 128x128 tile of W. LDS-staged A,B slices; 8x8 register tile
// rank-64 outer product in fp32; NF4 LUT from LDS; fused half8 store.
#define PWP 132  // padded leading dim (16B-aligned rows, bank-shift 4)
__global__ __launch_bounds__(256) void prep_w(const float* __restrict__ lora_A,
                                              const float* __restrict__ lora_B,
                                              const float* __restrict__ absmax,
                                              const int* __restrict__ codes,
                                              _Float16* __restrict__ Wc) {
  __shared__ float At[64 * PWP];  // At[r][ii] = lora_A[r][i0+ii]
  __shared__ float Bt[64 * PWP];  // Bt[r][oo] = lora_B[o0+oo][r]
  __shared__ float nf4s[16];
  const int tid = threadIdx.x;
  const int bxi = blockIdx.x & 31;   // i-tile (4096/128)
  const int byo = blockIdx.x >> 5;   // o-tile
  const int i0 = bxi * 128;
  const int o0 = byo * 128;
  if (tid < 16) nf4s[tid] = NF4C[tid];
  for (int idx = tid; idx < 8192; idx += 256) {
    int r = idx >> 7, ii = idx & 127;
    At[r * PWP + ii] = lora_A[(size_t)r * 4096 + i0 + ii];
  }
  for (int idx = tid; idx < 8192; idx += 256) {
    int oo = idx >> 6, r = idx & 63;
    Bt[r * PWP + oo] = lora_B[(size_t)(o0 + oo) * 64 + r];
  }
  __syncthreads();
  const int tx = tid & 15;   // col group: cols tx*8..+8
  const int ty = tid >> 4;   // row group: rows ty*8..+8
  float accw[8][8];
#pragma unroll
  for (int i = 0; i < 8; ++i)
#pragma unroll
    for (int j = 0; j < 8; ++j) accw[i][j] = 0.0f;
  for (int r = 0; r < 64; ++r) {
    float4 a0 = *(const float4*)&At[r * PWP + tx * 8];
    float4 a1 = *(const float4*)&At[r * PWP + tx * 8 + 4];
    float4 b0 = *(const float4*)&Bt[r * PWP + ty * 8];
    float4 b1 = *(const float4*)&Bt[r * PWP + ty * 8 + 4];
    float av[8] = {a0.x, a0.y, a0.z, a0.w, a1.x, a1.y, a1.z, a1.w};
    float bv[8] = {b0.x, b0.y, b0.z, b0.w, b1.x, b1.y, b1.z, b1.w};
#pragma unroll
    for (int i = 0; i < 8; ++i)
#pragma unroll
      for (int j = 0; j < 8; ++j) accw[i][j] += bv[i] * av[j];
  }
#pragma unroll
  for (int i = 0; i < 8; ++i) {
    const int o_g = o0 + ty * 8 + i;
    const int* crow = codes + (size_t)o_g * 4096 + i0 + tx * 8;
    int4 c0 = *(const int4*)crow;
    int4 c1 = *(const int4*)(crow + 4);
    // BK=64-aligned quant blocks: one absmax covers this thread's 8 cols
    const float am = absmax[o_g * 64 + (i0 >> 6) + (tx >> 3)];
    half8 h;
    h[0] = (_Float16)(nf4s[c0.x] * am + 2.0f * accw[i][0]);
    h[1] = (_Float16)(nf4s[c0.y] * am + 2.0f * accw[i][1]);
    h[2] = (_Float16)(nf4s[c0.z] * am + 2.0f * accw[i][2]);
    h[3] = (_Float16)(nf4s[c0.w] * am + 2.0f * accw[i][3]);
    h[4] = (_Float16)(nf4s[c1.x] * am + 2.0f * accw[i][4]);
    h[5] = (_Float16)(nf4s[c1.y] * am + 2.0f * accw[i][5]);
    h[6] = (_Float16)(nf4s[c1.z] * am + 2.0f * accw[i][6]);
    h[7] = (_Float16)(nf4s[c1.w] * am + 2.0f * accw[i][7]);
    *(half8*)(Wc + (size_t)o_g * 4096 + i0 + tx * 8) = h;
  }
}

// ---------------- gemm: C[M,N] = Xh[M,K] * Wc[N,K]^T (f16 MFMA) ----------------
__global__ __launch_bounds__(256, 2) void gemm(const _Float16* __restrict__ Xh,
                                               const _Float16* __restrict__ Wc,
                                               float* __restrict__ out) {
  __shared__ _Float16 As[128 * 32];  // [row m][k] row-major, 64B rows (no pad: global_load_lds)
  __shared__ _Float16 Bs[128 * 32];  // [row n][k]
  const int tid = threadIdx.x;
  const int lane = tid & 63;
  const int w = tid >> 6;            // wave 0..3
  const int bx = blockIdx.x & 31;    // n-tile (4096/128)
  const int by = blockIdx.x >> 5;    // m-tile (8192/128)
  const int wm = (w >> 1) * 64;      // wave's 64x64 region
  const int wn = (w & 1) * 64;
  const int m16 = lane & 15;
  const int quad = lane >> 4;

  // staging: each wave stages chunks {2w, 2w+1} (16 rows x 64B each) of As and Bs
  // lane L -> row L/4, col halves (L&3)*8  => lds elem off = chunk*512 + L*8 (HW: base+L*16B)
  const _Float16* gA = Xh + (size_t)(by * 128 + w * 32 + (lane >> 2)) * K_DIM + (lane & 3) * 8;
  const _Float16* gB = Wc + (size_t)(bx * 128 + w * 32 + (lane >> 2)) * K_DIM + (lane & 3) * 8;
  _Float16* sA = As + w * 1024;
  _Float16* sB = Bs + w * 1024;
  // fragment pointers: A-op lane layout m=lane&15, k=quad*8+j (8 contiguous halves)
  const _Float16* fa = As + (wm + m16) * 32 + quad * 8;
  const _Float16* fb = Bs + (wn + m16) * 32 + quad * 8;

  f32x4 acc[4][4];
#pragma unroll
  for (int mt = 0; mt < 4; ++mt)
#pragma unroll
    for (int nt = 0; nt < 4; ++nt) acc[mt][nt] = (f32x4){0.f, 0.f, 0.f, 0.f};

  for (int kt = 0; kt < K_DIM / 32; ++kt) {
    const _Float16* pa = gA + kt * 32;
    const _Float16* pb = gB + kt * 32;
    gl16(sA, pa);
    gl16(sA + 512, pa + 16 * K_DIM);
    gl16(sB, pb);
    gl16(sB + 512, pb + 16 * K_DIM);
    __syncthreads();  // drains vmcnt -> LDS tiles ready
    half8 a0 = *(const half8*)(fa);
    half8 a1 = *(const half8*)(fa + 512);
    half8 a2 = *(const half8*)(fa + 1024);
    half8 a3 = *(const half8*)(fa + 1536);
    half8 b0 = *(const half8*)(fb);
    half8 b1 = *(const half8*)(fb + 512);
    half8 b2 = *(const half8*)(fb + 1024);
    half8 b3 = *(const half8*)(fb + 1536);
    acc[0][0] = __builtin_amdgcn_mfma_f32_16x16x32_f16(a0, b0, acc[0][0], 0, 0, 0);
    acc[0][1] = __builtin_amdgcn_mfma_f32_16x16x32_f16(a0, b1, acc[0][1], 0, 0, 0);
    acc[0][2] = __builtin_amdgcn_mfma_f32_16x16x32_f16(a0, b2, acc[0][2], 0, 0, 0);
    acc[0][3] = __builtin_amdgcn_mfma_f32_16x16x32_f16(a0, b3, acc[0][3], 0, 0, 0);
    acc[1][0] = __builtin_amdgcn_mfma_f32_16x16x32_f16(a1, b0, acc[1][0], 0, 0, 0);
    acc[1][1] = __builtin_amdgcn_mfma_f32_16x16x32_f16(a1, b1, acc[1][1], 0, 0, 0);
    acc[1][2] = __builtin_amdgcn_mfma_f32_16x16x32_f16(a1, b2, acc[1][2], 0, 0, 0);
    acc[1][3] = __builtin_amdgcn_mfma_f32_16x16x32_f16(a1, b3, acc[1][3], 0, 0, 0);
    acc[2][0] = __builtin_amdgcn_mfma_f32_16x16x32_f16(a2, b0, acc[2][0], 0, 0, 0);
    acc[2][1] = __builtin_amdgcn_mfma_f32_16x16x32_f16(a2, b1, acc[2][1], 0, 0, 0);
    acc[2][2] = __builtin_amdgcn_mfma_f32_16x16x32_f16(a2, b2, acc[2][2], 0, 0, 0);
    acc[2][3] = __builtin_amdgcn_mfma_f32_16x16x32_f16(a2, b3, acc[2][3], 0, 0, 0);
    acc[3][0] = __builtin_amdgcn_mfma_f32_16x16x32_f16(a3, b0, acc[3][0], 0, 0, 0);
    acc[3][1] = __builtin_amdgcn_mfma_f32_16x16x32_f16(a3, b1, acc[3][1], 0, 0, 0);
    acc[3][2] = __builtin_amdgcn_mfma_f32_16x16x32_f16(a3, b2, acc[3][2], 0, 0, 0);
    acc[3][3] = __builtin_amdgcn_mfma_f32_16x16x32_f16(a3, b3, acc[3][3], 0, 0, 0);
    __syncthreads();  // all reads done before next stage overwrites
  }

  // epilogue: C/D layout col=lane&15, row=quad*4+reg
  const size_t rowbase = (size_t)by * 128 + wm + quad * 4;
  const int colbase = bx * 128 + wn + m16;
#pragma unroll
  for (int mt = 0; mt < 4; ++mt) {
#pragma unroll
    for (int r = 0; r < 4; ++r) {
      float* po = out + (rowbase + mt * 16 + r) * N_DIM + colbase;
      po[0]  = acc[mt][0][r];
      po[16] = acc[mt][1][r];
      po[32] = acc[mt][2][r];
      po[48] = acc[mt][3][r];
    }
  }
}

extern "C" void kernel_launch(void* const* d_in, const int* in_sizes, int n_in,
                              void* d_out, int out_size, void* d_ws, size_t ws_size,
                              hipStream_t stream) {
  const float* x      = (const float*)d_in[0];
  const float* lora_A = (const float*)d_in[1];
  const float* lora_B = (const float*)d_in[2];
  const float* absmax = (const float*)d_in[3];
  const int*   codes  = (const int*)d_in[4];
  float* out = (float*)d_out;

  _Float16* Xh = (_Float16*)d_ws;                    // 8192*4096 f16 = 64 MiB
  _Float16* Wc = Xh + (size_t)M_DIM * K_DIM;         // 4096*4096 f16 = 32 MiB

  hipLaunchKernelGGL(prep_x, dim3((M_DIM * K_DIM) / (8 * 256)), dim3(256), 0, stream,
                     (const float4*)x, (half8*)Xh);
  hipLaunchKernelGGL(prep_w, dim3((N_DIM / 128) * (K_DIM / 128)), dim3(256), 0, stream,
                     lora_A, lora_B, absmax, codes, Wc);
  hipLaunchKernelGGL(gemm, dim3((N_DIM / 128) * (M_DIM / 128)), dim3(256), 0, stream,
                     Xh, Wc, out);
}

// Round 2
// 605.428 us; speedup vs baseline: 1.0089x; 1.0089x over previous
//
#include <hip/hip_runtime.h>

// LoraLinear NF4: out = x @ W_eff^T, W_eff = NF4[codes]*absmax + 2*(lora_B @ lora_A)
// M=8192 (4*2048), N=4096, K=4096. f16 MFMA GEMM (m97 structure: 128x128 tile,
// BK=32, 4 waves, 4x4 acc/wave, global_load_lds width=16).
// R2: LDS chunk swizzle pc=(c+(row>>1))&3 to kill 8-way bank conflicts on
// fragment ds_read_b128 (SQ_LDS_BANK_CONFLICT was 3.35e7 ~= 16% of cycles).

typedef _Float16 half8 __attribute__((ext_vector_type(8)));
typedef float f32x4 __attribute__((ext_vector_type(4)));

#define M_DIM 8192
#define N_DIM 4096
#define K_DIM 4096

__constant__ float NF4C[16] = {
    -1.0f, -0.6961928009986877f, -0.5250730514526367f, -0.39491748809814453f,
    -0.28444138169288635f, -0.18477343022823334f, -0.09105003625154495f, 0.0f,
    0.07958029955625534f, 0.16093020141124725f, 0.24611230194568634f, 0.33791524171829224f,
    0.44070982933044434f, 0.5626170039176941f, 0.7229568362236023f, 1.0f};

__device__ __forceinline__ void gl16(void* lds, const void* g) {
  // async global->LDS, 16B/lane; LDS dest = wave-uniform base + lane*16
  __builtin_amdgcn_global_load_lds(
      (const __attribute__((address_space(1))) void*)g,
      (__attribute__((address_space(3))) void*)lds, 16, 0, 0);
}

// ---------------- prep_x: fp32 -> f16 cast of x ----------------
__global__ __launch_bounds__(256) void prep_x(const float4* __restrict__ x,
                                              half8* __restrict__ xh) {
  size_t i = (size_t)blockIdx.x * 256 + threadIdx.x;  // one half8 (8 elems) per thread
  float4 a = x[2 * i];
  float4 b = x[2 * i + 1];
  half8 h;
  h[0] = (_Float16)a.x; h[1] = (_Float16)a.y; h[2] = (_Float16)a.z; h[3] = (_Float16)a.w;
  h[4] = (_Float16)b.x; h[5] = (_Float16)b.y; h[6] = (_Float16)b.z; h[7] = (_Float16)b.w;
  xh[i] = h;
}

// ---------------- prep_w: dequant NF4 + fold 2*B@A, write f16 ----------------
#define PWP 132  // padded leading dim
__global__ __launch_bounds__(256) void prep_w(const float* __restrict__ lora_A,
                                              const float* __restrict__ lora_B,
                                              const float* __restrict__ absmax,
                                              const int* __restrict__ codes,
                                              _Float16* __restrict__ Wc) {
  __shared__ float At[64 * PWP];  // At[r][ii] = lora_A[r][i0+ii]
  __shared__ float Bt[64 * PWP];  // Bt[r][oo] = lora_B[o0+oo][r]
  __shared__ float nf4s[16];
  const int tid = threadIdx.x;
  const int bxi = blockIdx.x & 31;   // i-tile (4096/128)
  const int byo = blockIdx.x >> 5;   // o-tile
  const int i0 = bxi * 128;
  const int o0 = byo * 128;
  if (tid < 16) nf4s[tid] = NF4C[tid];
  for (int idx = tid; idx < 8192; idx += 256) {
    int r = idx >> 7, ii = idx & 127;
    At[r * PWP + ii] = lora_A[(size_t)r * 4096 + i0 + ii];
  }
  for (int idx = tid; idx < 8192; idx += 256) {
    int oo = idx >> 6, r = idx & 63;
    Bt[r * PWP + oo] = lora_B[(size_t)(o0 + oo) * 64 + r];
  }
  __syncthreads();
  const int tx = tid & 15;   // col group: cols tx*8..+8
  const int ty = tid >> 4;   // row group: rows ty*8..+8
  float accw[8][8];
#pragma unroll
  for (int i = 0; i < 8; ++i)
#pragma unroll
    for (int j = 0; j < 8; ++j) accw[i][j] = 0.0f;
  for (int r = 0; r < 64; ++r) {
    float4 a0 = *(const float4*)&At[r * PWP + tx * 8];
    float4 a1 = *(const float4*)&At[r * PWP + tx * 8 + 4];
    float4 b0 = *(const float4*)&Bt[r * PWP + ty * 8];
    float4 b1 = *(const float4*)&Bt[r * PWP + ty * 8 + 4];
    float av[8] = {a0.x, a0.y, a0.z, a0.w, a1.x, a1.y, a1.z, a1.w};
    float bv[8] = {b0.x, b0.y, b0.z, b0.w, b1.x, b1.y, b1.z, b1.w};
#pragma unroll
    for (int i = 0; i < 8; ++i)
#pragma unroll
      for (int j = 0; j < 8; ++j) accw[i][j] += bv[i] * av[j];
  }
#pragma unroll
  for (int i = 0; i < 8; ++i) {
    const int o_g = o0 + ty * 8 + i;
    const int* crow = codes + (size_t)o_g * 4096 + i0 + tx * 8;
    int4 c0 = *(const int4*)crow;
    int4 c1 = *(const int4*)(crow + 4);
    const float am = absmax[o_g * 64 + (i0 >> 6) + (tx >> 3)];
    half8 h;
    h[0] = (_Float16)(nf4s[c0.x] * am + 2.0f * accw[i][0]);
    h[1] = (_Float16)(nf4s[c0.y] * am + 2.0f * accw[i][1]);
    h[2] = (_Float16)(nf4s[c0.z] * am + 2.0f * accw[i][2]);
    h[3] = (_Float16)(nf4s[c0.w] * am + 2.0f * accw[i][3]);
    h[4] = (_Float16)(nf4s[c1.x] * am + 2.0f * accw[i][4]);
    h[5] = (_Float16)(nf4s[c1.y] * am + 2.0f * accw[i][5]);
    h[6] = (_Float16)(nf4s[c1.z] * am + 2.0f * accw[i][6]);
    h[7] = (_Float16)(nf4s[c1.w] * am + 2.0f * accw[i][7]);
    *(half8*)(Wc + (size_t)o_g * 4096 + i0 + tx * 8) = h;
  }
}

// ---------------- gemm: C[M,N] = Xh[M,K] * Wc[N,K]^T (f16 MFMA) ----------------
// LDS layout: row-major [128 rows][32 halves], 64B rows = 4 chunks of 16B.
// Swizzle: logical chunk c of row r stored at physical chunk (c + (r>>1)) & 3.
__global__ __launch_bounds__(256, 2) void gemm(const _Float16* __restrict__ Xh,
                                               const _Float16* __restrict__ Wc,
                                               float* __restrict__ out) {
  __shared__ _Float16 As[128 * 32];
  __shared__ _Float16 Bs[128 * 32];
  const int tid = threadIdx.x;
  const int lane = tid & 63;
  const int w = tid >> 6;            // wave 0..3
  const int bx = blockIdx.x & 31;    // n-tile (4096/128)
  const int by = blockIdx.x >> 5;    // m-tile (8192/128)
  const int wm = (w >> 1) * 64;      // wave's 64x64 region
  const int wn = (w & 1) * 64;
  const int m16 = lane & 15;
  const int quad = lane >> 4;

  // staging: wave w stages rows [w*32, w*32+32). Lane L writes physical LDS
  // slot (row = base + L/4, physchunk = L&3); source = logical chunk
  // c = (physchunk - (row>>1)) & 3. Row offset +16 between the two gl16 calls
  // leaves (row>>1)&3 unchanged, so one swizzled column offset serves both.
  const int srow = w * 32 + (lane >> 2);
  const int scol = ((lane & 3) - (lane >> 3)) & 3;  // ((L&3) - ((L>>2)>>1)) & 3
  const _Float16* gA = Xh + (size_t)(by * 128 + srow) * K_DIM + scol * 8;
  const _Float16* gB = Wc + (size_t)(bx * 128 + srow) * K_DIM + scol * 8;
  _Float16* sA = As + w * 1024;
  _Float16* sB = Bs + w * 1024;

  // fragment reads: lane wants logical chunk `quad` of row (wm+m16+16t);
  // physchunk = (quad + (row>>1)) & 3; invariant under row+=16 and wm (mult of 64).
  const int fchunk = (quad + (m16 >> 1)) & 3;
  const _Float16* fa = As + (wm + m16) * 32 + fchunk * 8;
  const _Float16* fb = Bs + (wn + m16) * 32 + fchunk * 8;

  f32x4 acc[4][4];
#pragma unroll
  for (int mt = 0; mt < 4; ++mt)
#pragma unroll
    for (int nt = 0; nt < 4; ++nt) acc[mt][nt] = (f32x4){0.f, 0.f, 0.f, 0.f};

  for (int kt = 0; kt < K_DIM / 32; ++kt) {
    const _Float16* pa = gA + kt * 32;
    const _Float16* pb = gB + kt * 32;
    gl16(sA, pa);
    gl16(sA + 512, pa + 16 * K_DIM);
    gl16(sB, pb);
    gl16(sB + 512, pb + 16 * K_DIM);
    __syncthreads();  // drains vmcnt -> LDS tiles ready
    half8 a0 = *(const half8*)(fa);
    half8 a1 = *(const half8*)(fa + 512);
    half8 a2 = *(const half8*)(fa + 1024);
    half8 a3 = *(const half8*)(fa + 1536);
    half8 b0 = *(const half8*)(fb);
    half8 b1 = *(const half8*)(fb + 512);
    half8 b2 = *(const half8*)(fb + 1024);
    half8 b3 = *(const half8*)(fb + 1536);
    acc[0][0] = __builtin_amdgcn_mfma_f32_16x16x32_f16(a0, b0, acc[0][0], 0, 0, 0);
    acc[0][1] = __builtin_amdgcn_mfma_f32_16x16x32_f16(a0, b1, acc[0][1], 0, 0, 0);
    acc[0][2] = __builtin_amdgcn_mfma_f32_16x16x32_f16(a0, b2, acc[0][2], 0, 0, 0);
    acc[0][3] = __builtin_amdgcn_mfma_f32_16x16x32_f16(a0, b3, acc[0][3], 0, 0, 0);
    acc[1][0] = __builtin_amdgcn_mfma_f32_16x16x32_f16(a1, b0, acc[1][0], 0, 0, 0);
    acc[1][1] = __builtin_amdgcn_mfma_f32_16x16x32_f16(a1, b1, acc[1][1], 0, 0, 0);
    acc[1][2] = __builtin_amdgcn_mfma_f32_16x16x32_f16(a1, b2, acc[1][2], 0, 0, 0);
    acc[1][3] = __builtin_amdgcn_mfma_f32_16x16x32_f16(a1, b3, acc[1][3], 0, 0, 0);
    acc[2][0] = __builtin_amdgcn_mfma_f32_16x16x32_f16(a2, b0, acc[2][0], 0, 0, 0);
    acc[2][1] = __builtin_amdgcn_mfma_f32_16x16x32_f16(a2, b1, acc[2][1], 0, 0, 0);
    acc[2][2] = __builtin_amdgcn_mfma_f32_16x16x32_f16(a2, b2, acc[2][2], 0, 0, 0);
    acc[2][3] = __builtin_amdgcn_mfma_f32_16x16x32_f16(a2, b3, acc[2][3], 0, 0, 0);
    acc[3][0] = __builtin_amdgcn_mfma_f32_16x16x32_f16(a3, b0, acc[3][0], 0, 0, 0);
    acc[3][1] = __builtin_amdgcn_mfma_f32_16x16x32_f16(a3, b1, acc[3][1], 0, 0, 0);
    acc[3][2] = __builtin_amdgcn_mfma_f32_16x16x32_f16(a3, b2, acc[3][2], 0, 0, 0);
    acc[3][3] = __builtin_amdgcn_mfma_f32_16x16x32_f16(a3, b3, acc[3][3], 0, 0, 0);
    __syncthreads();  // all reads done before next stage overwrites
  }

  // epilogue: C/D layout col=lane&15, row=quad*4+reg
  const size_t rowbase = (size_t)by * 128 + wm + quad * 4;
  const int colbase = bx * 128 + wn + m16;
#pragma unroll
  for (int mt = 0; mt < 4; ++mt) {
#pragma unroll
    for (int r = 0; r < 4; ++r) {
      float* po = out + (rowbase + mt * 16 + r) * N_DIM + colbase;
      po[0]  = acc[mt][0][r];
      po[16] = acc[mt][1][r];
      po[32] = acc[mt][2][r];
      po[48] = acc[mt][3][r];
    }
  }
}

extern "C" void kernel_launch(void* const* d_in, const int* in_sizes, int n_in,
                              void* d_out, int out_size, void* d_ws, size_t ws_size,
                              hipStream_t stream) {
  const float* x      = (const float*)d_in[0];
  const float* lora_A = (const float*)d_in[1];
  const float* lora_B = (const float*)d_in[2];
  const float* absmax = (const float*)d_in[3];
  const int*   codes  = (const int*)d_in[4];
  float* out = (float*)d_out;

  _Float16* Xh = (_Float16*)d_ws;                    // 8192*4096 f16 = 64 MiB
  _Float16* Wc = Xh + (size_t)M_DIM * K_DIM;         // 4096*4096 f16 = 32 MiB

  hipLaunchKernelGGL(prep_x, dim3((M_DIM * K_DIM) / (8 * 256)), dim3(256), 0, stream,
                     (const float4*)x, (half8*)Xh);
  hipLaunchKernelGGL(prep_w, dim3((N_DIM / 128) * (K_DIM / 128)), dim3(256), 0, stream,
                     lora_A, lora_B, absmax, codes, Wc);
  hipLaunchKernelGGL(gemm, dim3((N_DIM / 128) * (M_DIM / 128)), dim3(256), 0, stream,
                     Xh, Wc, out);
}